// Round 1
// baseline (255.386 us; speedup 1.0000x reference)
//
#include <hip/hip_runtime.h>
#include <stdint.h>

// Problem constants
#define BB   2048   // batch
#define DIN  2048
#define UU   1024   // units
#define KF   49
#define GM   2048         // GEMM M = batch
#define GK   3072         // GEMM K = UU + DIN
#define GN   5120         // GEMM N = 5*UU

typedef __bf16  bf16x8 __attribute__((ext_vector_type(8)));
typedef float   f32x4  __attribute__((ext_vector_type(4)));

static __device__ __forceinline__ unsigned short f2bf(float f) {
    union { float f; unsigned u; } x; x.f = f;
    unsigned u = x.u;
    unsigned r = (u + 0x7fffu + ((u >> 16) & 1u)) >> 16;   // RNE
    return (unsigned short)r;
}

// ---------------------------------------------------------------------------
// Kernel 1: A = [h_tm | inputs] as bf16, row-major [GM][GK]
// ---------------------------------------------------------------------------
__global__ void buildA(const float* __restrict__ h, const float* __restrict__ x,
                       unsigned short* __restrict__ A) {
    int idx = blockIdx.x * blockDim.x + threadIdx.x;      // one thread = 4 elems
    int b = idx / (GK / 4);
    int k = (idx % (GK / 4)) * 4;
    float4 v;
    if (k < UU) v = *(const float4*)(h + (size_t)b * UU + k);
    else        v = *(const float4*)(x + (size_t)b * DIN + (k - UU));
    ushort4 o;
    o.x = f2bf(v.x); o.y = f2bf(v.y); o.z = f2bf(v.z); o.w = f2bf(v.w);
    *(ushort4*)(A + (size_t)idx * 4) = o;
}

// ---------------------------------------------------------------------------
// Kernel 2: Wt[n][k] = (k<UU ? W_gates[k][n] : U_gates[k-UU][n]) as bf16
// LDS-tiled 32x32 transpose. grid = (GK/32, GN/32)
// ---------------------------------------------------------------------------
__global__ void buildW(const float* __restrict__ Wg, const float* __restrict__ Ug,
                       unsigned short* __restrict__ Wt) {
    __shared__ float t[32][33];
    int k0 = blockIdx.x * 32, n0 = blockIdx.y * 32;
    int tx = threadIdx.x & 31, ty = threadIdx.x >> 5;     // ty in 0..7
#pragma unroll
    for (int r = 0; r < 4; r++) {
        int k = k0 + ty + r * 8;
        const float* src = (k < UU) ? (Wg + (size_t)k * GN) : (Ug + (size_t)(k - UU) * GN);
        t[ty + r * 8][tx] = src[n0 + tx];
    }
    __syncthreads();
#pragma unroll
    for (int r = 0; r < 4; r++) {
        int n = n0 + ty + r * 8;
        Wt[(size_t)n * GK + k0 + tx] = f2bf(t[tx][ty + r * 8]);
    }
}

// ---------------------------------------------------------------------------
// Kernel 3: Z[GM][GN] = A @ Wt^T   (bf16 MFMA 16x16x32, fp32 accum)
// m97 structure: 128x128 tile, BK=32, 4 waves (2x2), 4x4 frags/wave,
// global_load_lds width 16, linear LDS, 2-barrier K loop.
// grid = (GN/128, GM/128), block = 256
// ---------------------------------------------------------------------------
__global__ __launch_bounds__(256) void gemm_kernel(const unsigned short* __restrict__ A,
                                                   const unsigned short* __restrict__ Bt,
                                                   float* __restrict__ Z) {
    __shared__ __align__(16) char lds[16384];   // A tile [128][32] bf16 | B tile [128][32] bf16

    const int tid  = threadIdx.x;
    const int lane = tid & 63;
    const int wave = tid >> 6;
    const int wr = wave >> 1, wc = wave & 1;
    const int brow = blockIdx.y * 128;
    const int bcol = blockIdx.x * 128;

    f32x4 acc[4][4];
#pragma unroll
    for (int m = 0; m < 4; m++)
#pragma unroll
        for (int n = 0; n < 4; n++) acc[m][n] = (f32x4){0.f, 0.f, 0.f, 0.f};

    const int q0 = tid, q1 = tid + 256;
    const unsigned short* ga0 = A  + (size_t)(brow + (q0 >> 2)) * GK + (q0 & 3) * 8;
    const unsigned short* ga1 = A  + (size_t)(brow + (q1 >> 2)) * GK + (q1 & 3) * 8;
    const unsigned short* gb0 = Bt + (size_t)(bcol + (q0 >> 2)) * GK + (q0 & 3) * 8;
    const unsigned short* gb1 = Bt + (size_t)(bcol + (q1 >> 2)) * GK + (q1 & 3) * 8;

    // fragment LDS byte offsets (row stride 64B = 32 bf16)
    const int aoff = (wr * 64 + (lane & 15)) * 64 + (lane >> 4) * 16;
    const int boff = 8192 + (wc * 64 + (lane & 15)) * 64 + (lane >> 4) * 16;

    for (int k0 = 0; k0 < GK; k0 += 32) {
        __builtin_amdgcn_global_load_lds((const __attribute__((address_space(1))) void*)(ga0 + k0),
            (__attribute__((address_space(3))) void*)(lds + q0 * 16), 16, 0, 0);
        __builtin_amdgcn_global_load_lds((const __attribute__((address_space(1))) void*)(ga1 + k0),
            (__attribute__((address_space(3))) void*)(lds + q1 * 16), 16, 0, 0);
        __builtin_amdgcn_global_load_lds((const __attribute__((address_space(1))) void*)(gb0 + k0),
            (__attribute__((address_space(3))) void*)(lds + 8192 + q0 * 16), 16, 0, 0);
        __builtin_amdgcn_global_load_lds((const __attribute__((address_space(1))) void*)(gb1 + k0),
            (__attribute__((address_space(3))) void*)(lds + 8192 + q1 * 16), 16, 0, 0);
        __syncthreads();

        bf16x8 af[4], bfr[4];
#pragma unroll
        for (int m = 0; m < 4; m++) af[m]  = *(const bf16x8*)(lds + aoff + m * 1024);
#pragma unroll
        for (int n = 0; n < 4; n++) bfr[n] = *(const bf16x8*)(lds + boff + n * 1024);
#pragma unroll
        for (int m = 0; m < 4; m++)
#pragma unroll
            for (int n = 0; n < 4; n++)
                acc[m][n] = __builtin_amdgcn_mfma_f32_16x16x32_bf16(af[m], bfr[n], acc[m][n], 0, 0, 0);
        __syncthreads();
    }

    const int crow0 = brow + wr * 64 + ((lane >> 4) << 2);
    const int ccol0 = bcol + wc * 64 + (lane & 15);
#pragma unroll
    for (int m = 0; m < 4; m++)
#pragma unroll
        for (int n = 0; n < 4; n++)
#pragma unroll
            for (int j = 0; j < 4; j++)
                Z[(size_t)(crow0 + m * 16 + j) * GN + ccol0 + n * 16] = acc[m][n][j];
}

// ---------------------------------------------------------------------------
// Kernel 4: gates + cell + sentinel + ct (softmax over size-1 axis == 1,
// so ct = sum_k v_seq + st). grid = (BB), block = 256, 4 units/thread.
// out layout: [ht+ct][ht][mt], each [BB][UU] fp32.
// ---------------------------------------------------------------------------
__global__ void fused_tail(const float* __restrict__ Z, const float* __restrict__ m_tm,
                           const float* __restrict__ bg, const float* __restrict__ v_seq,
                           float* __restrict__ out) {
    const int b = blockIdx.x;
    const int u = threadIdx.x * 4;
    const float* zr = Z + (size_t)b * GN;

    float4 vf = *(const float4*)(zr + 0 * UU + u);
    float4 vi = *(const float4*)(zr + 1 * UU + u);
    float4 vo = *(const float4*)(zr + 2 * UU + u);
    float4 vg = *(const float4*)(zr + 3 * UU + u);
    float4 va = *(const float4*)(zr + 4 * UU + u);
    float4 b0 = *(const float4*)(bg + 0 * UU + u);
    float4 b1 = *(const float4*)(bg + 1 * UU + u);
    float4 b2 = *(const float4*)(bg + 2 * UU + u);
    float4 b3 = *(const float4*)(bg + 3 * UU + u);
    float4 b4 = *(const float4*)(bg + 4 * UU + u);
    float4 vm = *(const float4*)(m_tm + (size_t)b * UU + u);

    float ht[4], mt[4], st[4];
#pragma unroll
    for (int j = 0; j < 4; j++) {
        float f = ((const float*)&vf)[j] + ((const float*)&b0)[j];
        float i = ((const float*)&vi)[j] + ((const float*)&b1)[j];
        float o = ((const float*)&vo)[j] + ((const float*)&b2)[j];
        float g = ((const float*)&vg)[j] + ((const float*)&b3)[j];
        float a = ((const float*)&va)[j] + ((const float*)&b4)[j];
        float m = ((const float*)&vm)[j];
        float ft = 1.f / (1.f + __expf(-f));
        float it = 1.f / (1.f + __expf(-i));
        float ot = 1.f / (1.f + __expf(-o));
        float gt = 1.f / (1.f + __expf(-g));
        float at = tanhf(a);
        float mtv = m * ft + it * at;
        float tm = tanhf(mtv);
        mt[j] = mtv;
        ht[j] = ot * tm;
        st[j] = gt * tm;
    }

    // ct = sum_k v_seq[b,k,u..u+3] + st  (alpha == 1 since softmax axis has size 1)
    float c0 = st[0], c1 = st[1], c2 = st[2], c3 = st[3];
    const float* vp = v_seq + (size_t)b * KF * UU + u;
#pragma unroll 7
    for (int k = 0; k < KF; k++) {
        float4 v = *(const float4*)(vp + (size_t)k * UU);
        c0 += v.x; c1 += v.y; c2 += v.z; c3 += v.w;
    }

    float4 r0 = { ht[0] + c0, ht[1] + c1, ht[2] + c2, ht[3] + c3 };
    float4 r1 = { ht[0], ht[1], ht[2], ht[3] };
    float4 r2 = { mt[0], mt[1], mt[2], mt[3] };
    *(float4*)(out + (size_t)b * UU + u) = r0;
    *(float4*)(out + (size_t)GM * UU + (size_t)b * UU + u) = r1;
    *(float4*)(out + 2 * (size_t)GM * UU + (size_t)b * UU + u) = r2;
}

// ---------------------------------------------------------------------------
extern "C" void kernel_launch(void* const* d_in, const int* in_sizes, int n_in,
                              void* d_out, int out_size, void* d_ws, size_t ws_size,
                              hipStream_t stream) {
    (void)in_sizes; (void)n_in; (void)out_size; (void)ws_size;
    const float* inputs  = (const float*)d_in[0];
    const float* h_tm    = (const float*)d_in[1];
    const float* m_tm    = (const float*)d_in[2];
    const float* v_seq   = (const float*)d_in[3];
    const float* W_gates = (const float*)d_in[4];
    const float* U_gates = (const float*)d_in[5];
    const float* b_gates = (const float*)d_in[6];
    // d_in[7..9] (W_z, U_z, W_h) are dead: softmax over a size-1 axis == 1.

    char* ws = (char*)d_ws;
    unsigned short* Abf = (unsigned short*)ws;                          // 2048*3072*2  = 12,582,912 B
    unsigned short* Wt  = (unsigned short*)(ws + 12582912);             // 5120*3072*2  = 31,457,280 B
    float*          Zf  = (float*)(ws + 12582912 + 31457280);           // 2048*5120*4  = 41,943,040 B
    float* out = (float*)d_out;

    hipLaunchKernelGGL(buildA, dim3((GM * GK / 4) / 256), dim3(256), 0, stream, h_tm, inputs, Abf);
    hipLaunchKernelGGL(buildW, dim3(GK / 32, GN / 32), dim3(256), 0, stream, W_gates, U_gates, Wt);
    hipLaunchKernelGGL(gemm_kernel, dim3(GN / 128, GM / 128), dim3(256), 0, stream, Abf, Wt, Zf);
    hipLaunchKernelGGL(fused_tail, dim3(BB), dim3(256), 0, stream, Zf, m_tm, b_gates, v_seq, out);
}

// Round 2
// 223.304 us; speedup vs baseline: 1.1437x; 1.1437x over previous
//
#include <hip/hip_runtime.h>
#include <stdint.h>

// Problem constants
#define BB   2048
#define DIN  2048
#define UU   1024
#define KF   49
#define GM   2048         // GEMM M = batch
#define GK   3072         // GEMM K = UU + DIN
#define GN   5120         // GEMM N = 5*UU

typedef __bf16  bf16x8 __attribute__((ext_vector_type(8)));
typedef float   f32x4  __attribute__((ext_vector_type(4)));

static __device__ __forceinline__ unsigned short f2bf(float f) {
    union { float f; unsigned u; } x; x.f = f;
    unsigned u = x.u;
    unsigned r = (u + 0x7fffu + ((u >> 16) & 1u)) >> 16;   // RNE
    return (unsigned short)r;
}

// ---------------------------------------------------------------------------
// Kernel 1: prep = buildA (blocks [0,6144)) + buildW transpose (blocks [6144,21504))
//   A[b][k] = bf16([h_tm | inputs])          row-major [GM][GK]
//   Wt[n][k] = bf16(k<UU ? W_gates[k][n] : U_gates[k-UU][n])   [GN][GK]
// ---------------------------------------------------------------------------
__global__ void prep(const float* __restrict__ h, const float* __restrict__ x,
                     const float* __restrict__ Wg, const float* __restrict__ Ug,
                     unsigned short* __restrict__ A, unsigned short* __restrict__ Wt) {
    __shared__ float t[32][36];   // +4 pad keeps float4 alignment and spreads banks
    if (blockIdx.x < 6144) {
        int idx = blockIdx.x * 256 + threadIdx.x;    // one thread = 4 elems
        int b = idx / (GK / 4);
        int k = (idx % (GK / 4)) * 4;
        float4 v;
        if (k < UU) v = *(const float4*)(h + (size_t)b * UU + k);
        else        v = *(const float4*)(x + (size_t)b * DIN + (k - UU));
        ushort4 o;
        o.x = f2bf(v.x); o.y = f2bf(v.y); o.z = f2bf(v.z); o.w = f2bf(v.w);
        *(ushort4*)(A + (size_t)idx * 4) = o;
    } else {
        int bid2 = blockIdx.x - 6144;                // 32x32 transpose tiles
        int k0 = (bid2 % (GK / 32)) * 32;
        int n0 = (bid2 / (GK / 32)) * 32;
        int r  = threadIdx.x >> 3;                   // 0..31
        int cq = threadIdx.x & 7;                    // 0..7  (x4 floats)
        int k = k0 + r;
        const float* src = (k < UU) ? (Wg + (size_t)k * GN) : (Ug + (size_t)(k - UU) * GN);
        *(float4*)&t[r][cq * 4] = *(const float4*)(src + n0 + cq * 4);
        __syncthreads();
        ushort4 o;
        o.x = f2bf(t[cq * 4 + 0][r]);
        o.y = f2bf(t[cq * 4 + 1][r]);
        o.z = f2bf(t[cq * 4 + 2][r]);
        o.w = f2bf(t[cq * 4 + 3][r]);
        *(ushort4*)(Wt + (size_t)(n0 + r) * GK + k0 + cq * 4) = o;
    }
}

// ---------------------------------------------------------------------------
// Kernel 2: vsum[b][u] = sum_k v_seq[b][k][u]   (alpha==1: softmax over size-1 axis)
// ---------------------------------------------------------------------------
__global__ void vsum_kernel(const float* __restrict__ v_seq, float* __restrict__ vsum) {
    const int b = blockIdx.x;
    const int u = threadIdx.x * 4;
    const float* vp = v_seq + (size_t)b * KF * UU + u;
    float4 a = *(const float4*)(vp);
#pragma unroll 8
    for (int k = 1; k < KF; k++) {
        float4 v = *(const float4*)(vp + (size_t)k * UU);
        a.x += v.x; a.y += v.y; a.z += v.z; a.w += v.w;
    }
    *(float4*)(vsum + (size_t)b * UU + u) = a;
}

// ---------------------------------------------------------------------------
// Kernel 3: fused 5-gate GEMM + LSTM tail.
// Block tile: 128 batch-rows x 32 unit-cols x 5 gates (effective 128x160 GEMM tile).
// 4 waves (2 row x 2 ucol), acc[4][5] f32x4 per wave. BK=32, m97 2-barrier loop,
// global_load_lds width 16. Epilogue computes gates -> ht/mt/st, adds vsum, writes
// all 3 outputs. Z never touches HBM.
// grid = (UU/32, GM/128) = (32,16), block = 256.
// ---------------------------------------------------------------------------
__global__ __launch_bounds__(256, 2) void gemm_fused(
        const unsigned short* __restrict__ A, const unsigned short* __restrict__ Wt,
        const float* __restrict__ m_tm, const float* __restrict__ bg,
        const float* __restrict__ vsum, float* __restrict__ out) {
    // LDS: A tile [128][32]bf16 = 8KB at 0 | B tiles [5][32 rows][32 k]bf16 = 10KB at 8192
    __shared__ __align__(16) char lds[18432];

    const int tid  = threadIdx.x;
    const int lane = tid & 63;
    const int wave = tid >> 6;
    const int wr = wave >> 1, wc = wave & 1;
    const int brow  = blockIdx.y * 128;
    const int ucol0 = blockIdx.x * 32;

    f32x4 acc[4][5];
#pragma unroll
    for (int m = 0; m < 4; m++)
#pragma unroll
        for (int g = 0; g < 5; g++) acc[m][g] = (f32x4){0.f, 0.f, 0.f, 0.f};

    // Staging: 1152 chunks of 16B per K-step (A: 512, B: 640).
    // Wave-round t: chunks [t*256 + wave*64, +64). Each lane takes chunk base+lane.
    const unsigned short* src[5];
    int ldsoff[5];
    bool valid[5];
#pragma unroll
    for (int t = 0; t < 5; t++) {
        int base = t * 256 + wave * 64;
        int j = base + lane;
        valid[t]  = (base < 1152);
        ldsoff[t] = j * 16;
        if (j < 512) {
            // A chunk: row = j>>2, k-part = (j&3)*8
            src[t] = A + (size_t)(brow + (j >> 2)) * GK + (j & 3) * 8;
        } else {
            int j2 = j - 512;                  // gate g, local col n, k-part c
            int g = j2 >> 7;
            int n = (j2 >> 2) & 31;
            int c = j2 & 3;
            int gg = (g > 4) ? 4 : g;          // clamp (only hit on invalid t)
            src[t] = Wt + ((size_t)gg * UU + ucol0 + n) * GK + c * 8;
        }
    }

    for (int k0 = 0; k0 < GK; k0 += 32) {
#pragma unroll
        for (int t = 0; t < 5; t++)
            if (valid[t])
                __builtin_amdgcn_global_load_lds(
                    (const __attribute__((address_space(1))) void*)(src[t] + k0),
                    (__attribute__((address_space(3))) void*)(lds + ldsoff[t]), 16, 0, 0);
        __syncthreads();

        bf16x8 af[4], bfg[5];
#pragma unroll
        for (int m = 0; m < 4; m++)
            af[m] = *(const bf16x8*)(lds + (wr * 64 + m * 16 + (lane & 15)) * 64 + (lane >> 4) * 16);
#pragma unroll
        for (int g = 0; g < 5; g++)
            bfg[g] = *(const bf16x8*)(lds + 8192 + g * 2048 + (wc * 16 + (lane & 15)) * 64 + (lane >> 4) * 16);
#pragma unroll
        for (int m = 0; m < 4; m++)
#pragma unroll
            for (int g = 0; g < 5; g++)
                acc[m][g] = __builtin_amdgcn_mfma_f32_16x16x32_bf16(af[m], bfg[g], acc[m][g], 0, 0, 0);
        __syncthreads();
    }

    // Epilogue: gates + cell + sentinel + ct, write 3 outputs.
    const int ucol = ucol0 + wc * 16 + (lane & 15);
    const float b0 = bg[0 * UU + ucol];
    const float b1 = bg[1 * UU + ucol];
    const float b2 = bg[2 * UU + ucol];
    const float b3 = bg[3 * UU + ucol];
    const float b4 = bg[4 * UU + ucol];
    const int r0 = brow + wr * 64 + ((lane >> 4) << 2);
    float* out0 = out;
    float* out1 = out + (size_t)GM * UU;
    float* out2 = out + 2 * (size_t)GM * UU;
#pragma unroll
    for (int m = 0; m < 4; m++) {
#pragma unroll
        for (int j = 0; j < 4; j++) {
            const int row = r0 + m * 16 + j;
            const size_t idx = (size_t)row * UU + ucol;
            const float mtm = m_tm[idx];
            const float vs  = vsum[idx];
            const float f = acc[m][0][j] + b0;
            const float i = acc[m][1][j] + b1;
            const float o = acc[m][2][j] + b2;
            const float g = acc[m][3][j] + b3;
            const float a = acc[m][4][j] + b4;
            const float ft = 1.f / (1.f + __expf(-f));
            const float it = 1.f / (1.f + __expf(-i));
            const float ot = 1.f / (1.f + __expf(-o));
            const float gt = 1.f / (1.f + __expf(-g));
            const float at = tanhf(a);
            const float mtv = mtm * ft + it * at;
            const float tm  = tanhf(mtv);
            const float ht  = ot * tm;
            const float st  = gt * tm;
            out0[idx] = ht + vs + st;
            out1[idx] = ht;
            out2[idx] = mtv;
        }
    }
}

// ---------------------------------------------------------------------------
extern "C" void kernel_launch(void* const* d_in, const int* in_sizes, int n_in,
                              void* d_out, int out_size, void* d_ws, size_t ws_size,
                              hipStream_t stream) {
    (void)in_sizes; (void)n_in; (void)out_size; (void)ws_size;
    const float* inputs  = (const float*)d_in[0];
    const float* h_tm    = (const float*)d_in[1];
    const float* m_tm    = (const float*)d_in[2];
    const float* v_seq   = (const float*)d_in[3];
    const float* W_gates = (const float*)d_in[4];
    const float* U_gates = (const float*)d_in[5];
    const float* b_gates = (const float*)d_in[6];
    // d_in[7..9] (W_z, U_z, W_h) are dead: softmax over a size-1 axis == 1.

    char* ws = (char*)d_ws;
    unsigned short* Abf = (unsigned short*)ws;                  // 2048*3072*2 = 12,582,912 B
    unsigned short* Wt  = (unsigned short*)(ws + 12582912);     // 5120*3072*2 = 31,457,280 B
    float*          vs  = (float*)(ws + 12582912 + 31457280);   // 2048*1024*4 =  8,388,608 B
    float* out = (float*)d_out;

    hipLaunchKernelGGL(prep, dim3(6144 + (GK / 32) * (GN / 32)), dim3(256), 0, stream,
                       h_tm, inputs, W_gates, U_gates, Abf, Wt);
    hipLaunchKernelGGL(vsum_kernel, dim3(BB), dim3(256), 0, stream, v_seq, vs);
    hipLaunchKernelGGL(gemm_fused, dim3(UU / 32, GM / 128), dim3(256), 0, stream,
                       Abf, Wt, m_tm, b_gates, vs, out);
}

// Round 3
// 209.321 us; speedup vs baseline: 1.2201x; 1.0668x over previous
//
#include <hip/hip_runtime.h>
#include <stdint.h>

// Problem constants
#define BB   2048
#define DIN  2048
#define UU   1024
#define KF   49
#define GM   2048         // GEMM M = batch
#define GK   3072         // GEMM K = UU + DIN
#define GN   5120         // GEMM N = 5*UU

typedef __bf16  bf16x8 __attribute__((ext_vector_type(8)));
typedef float   f32x4  __attribute__((ext_vector_type(4)));

static __device__ __forceinline__ unsigned short f2bf(float f) {
    union { float f; unsigned u; } x; x.f = f;
    unsigned u = x.u;
    unsigned r = (u + 0x7fffu + ((u >> 16) & 1u)) >> 16;   // RNE
    return (unsigned short)r;
}

// ---------------------------------------------------------------------------
// Kernel 1: prep = buildA (blocks [0,6144)) + buildW transpose (blocks [6144,21504))
//   A[b][k] = bf16([h_tm | inputs])          row-major [GM][GK]
//   Wt[n][k] = bf16(k<UU ? W_gates[k][n] : U_gates[k-UU][n])   [GN][GK]
// ---------------------------------------------------------------------------
__global__ void prep(const float* __restrict__ h, const float* __restrict__ x,
                     const float* __restrict__ Wg, const float* __restrict__ Ug,
                     unsigned short* __restrict__ A, unsigned short* __restrict__ Wt) {
    __shared__ float t[32][36];
    if (blockIdx.x < 6144) {
        int idx = blockIdx.x * 256 + threadIdx.x;    // one thread = 4 elems
        int b = idx / (GK / 4);
        int k = (idx % (GK / 4)) * 4;
        float4 v;
        if (k < UU) v = *(const float4*)(h + (size_t)b * UU + k);
        else        v = *(const float4*)(x + (size_t)b * DIN + (k - UU));
        ushort4 o;
        o.x = f2bf(v.x); o.y = f2bf(v.y); o.z = f2bf(v.z); o.w = f2bf(v.w);
        *(ushort4*)(A + (size_t)idx * 4) = o;
    } else {
        int bid2 = blockIdx.x - 6144;                // 32x32 transpose tiles
        int k0 = (bid2 % (GK / 32)) * 32;
        int n0 = (bid2 / (GK / 32)) * 32;
        int r  = threadIdx.x >> 3;                   // 0..31
        int cq = threadIdx.x & 7;                    // 0..7  (x4 floats)
        int k = k0 + r;
        const float* src = (k < UU) ? (Wg + (size_t)k * GN) : (Ug + (size_t)(k - UU) * GN);
        *(float4*)&t[r][cq * 4] = *(const float4*)(src + n0 + cq * 4);
        __syncthreads();
        ushort4 o;
        o.x = f2bf(t[cq * 4 + 0][r]);
        o.y = f2bf(t[cq * 4 + 1][r]);
        o.z = f2bf(t[cq * 4 + 2][r]);
        o.w = f2bf(t[cq * 4 + 3][r]);
        *(ushort4*)(Wt + (size_t)(n0 + r) * GK + k0 + cq * 4) = o;
    }
}

// ---------------------------------------------------------------------------
// Kernel 2: fused 5-gate GEMM + v_seq reduction + LSTM tail.
// Block tile: 128 batch-rows x 32 unit-cols x 5 gates. 4 waves (2x2), acc[4][5].
// BK=32, m97 2-barrier loop, global_load_lds width 16.
// v_seq summation interleaved into the K-loop (2 float4/thread/iter, k=0..47;
// k=48 in epilogue), exchanged via LDS (stride-36 rows) to output owners.
// grid = (UU/32, GM/128) = (32,16), block = 256.
// ---------------------------------------------------------------------------
__global__ __launch_bounds__(256, 2) void gemm_fused(
        const unsigned short* __restrict__ A, const unsigned short* __restrict__ Wt,
        const float* __restrict__ m_tm, const float* __restrict__ bg,
        const float* __restrict__ v_seq, float* __restrict__ out) {
    // LDS: A tile [128][32]bf16 = 8KB at 0 | B tiles [5][32][32]bf16 = 10KB at 8192
    // Reused after the K-loop as lv[128][36] f32 (18432 B) for the v-sum exchange.
    __shared__ __align__(16) char lds[18432];

    const int tid  = threadIdx.x;
    const int lane = tid & 63;
    const int wave = tid >> 6;
    const int wr = wave >> 1, wc = wave & 1;
    const int brow  = blockIdx.y * 128;
    const int ucol0 = blockIdx.x * 32;

    f32x4 acc[4][5];
#pragma unroll
    for (int m = 0; m < 4; m++)
#pragma unroll
        for (int g = 0; g < 5; g++) acc[m][g] = (f32x4){0.f, 0.f, 0.f, 0.f};

    // --- staging descriptors (1152 chunks of 16B per K-step: A 512, B 640) ---
    const unsigned short* src[5];
    int ldsoff[5];
    bool valid[5];
#pragma unroll
    for (int t = 0; t < 5; t++) {
        int base = t * 256 + wave * 64;
        int j = base + lane;
        valid[t]  = (base < 1152);
        ldsoff[t] = j * 16;
        if (j < 512) {
            src[t] = A + (size_t)(brow + (j >> 2)) * GK + (j & 3) * 8;
        } else {
            int j2 = j - 512;
            int g = j2 >> 7;
            int n = (j2 >> 2) & 31;
            int c = j2 & 3;
            int gg = (g > 4) ? 4 : g;
            src[t] = Wt + ((size_t)gg * UU + ucol0 + n) * GK + c * 8;
        }
    }

    // --- v_seq accumulation state: thread covers rows (tid>>3)+32r, cols (tid&7)*4..+3 ---
    float4 vacc[4];
#pragma unroll
    for (int r = 0; r < 4; r++) vacc[r] = (float4){0.f, 0.f, 0.f, 0.f};
    const float* vp = v_seq + ((size_t)(brow + (tid >> 3)) * KF) * UU + ucol0 + (tid & 7) * 4;

    for (int k0 = 0; k0 < GK; k0 += 32) {
#pragma unroll
        for (int t = 0; t < 5; t++)
            if (valid[t])
                __builtin_amdgcn_global_load_lds(
                    (const __attribute__((address_space(1))) void*)(src[t] + k0),
                    (__attribute__((address_space(3))) void*)(lds + ldsoff[t]), 16, 0, 0);

        // interleaved v_seq partial loads: iter i=k0/32; even i -> rows r0,r1; odd -> r2,r3; k=i/2
        {
            const int kk = k0 >> 6;                         // i >> 1, 0..47
            const float4 va0 = *(const float4*)(vp + ((size_t)0  * KF + kk) * UU);
            const float4 va1 = *(const float4*)(vp + ((size_t)32 * KF + kk) * UU);
            const float4 vb0 = *(const float4*)(vp + ((size_t)64 * KF + kk) * UU);
            const float4 vb1 = *(const float4*)(vp + ((size_t)96 * KF + kk) * UU);
            if (((k0 >> 5) & 1) == 0) {
                vacc[0].x += va0.x; vacc[0].y += va0.y; vacc[0].z += va0.z; vacc[0].w += va0.w;
                vacc[1].x += va1.x; vacc[1].y += va1.y; vacc[1].z += va1.z; vacc[1].w += va1.w;
            } else {
                vacc[2].x += vb0.x; vacc[2].y += vb0.y; vacc[2].z += vb0.z; vacc[2].w += vb0.w;
                vacc[3].x += vb1.x; vacc[3].y += vb1.y; vacc[3].z += vb1.z; vacc[3].w += vb1.w;
            }
        }

        __syncthreads();

        bf16x8 af[4], bfg[5];
#pragma unroll
        for (int m = 0; m < 4; m++)
            af[m] = *(const bf16x8*)(lds + (wr * 64 + m * 16 + (lane & 15)) * 64 + (lane >> 4) * 16);
#pragma unroll
        for (int g = 0; g < 5; g++)
            bfg[g] = *(const bf16x8*)(lds + 8192 + g * 2048 + (wc * 16 + (lane & 15)) * 64 + (lane >> 4) * 16);
#pragma unroll
        for (int m = 0; m < 4; m++)
#pragma unroll
            for (int g = 0; g < 5; g++)
                acc[m][g] = __builtin_amdgcn_mfma_f32_16x16x32_bf16(af[m], bfg[g], acc[m][g], 0, 0, 0);
        __syncthreads();
    }

    // leftover v_seq k = 48
#pragma unroll
    for (int r = 0; r < 4; r++) {
        const float4 v = *(const float4*)(vp + ((size_t)(32 * r) * KF + 48) * UU);
        vacc[r].x += v.x; vacc[r].y += v.y; vacc[r].z += v.z; vacc[r].w += v.w;
    }

    // exchange v-sums via LDS: lv[row][col], row stride 36 floats
    float* lv = (float*)lds;
    {
        const int lr = tid >> 3, lc = (tid & 7) * 4;
#pragma unroll
        for (int r = 0; r < 4; r++)
            *(float4*)&lv[(size_t)(lr + 32 * r) * 36 + lc] = vacc[r];
    }
    __syncthreads();

    // Epilogue: gates + cell + sentinel + ct, write 3 outputs.
    const int ucol = ucol0 + wc * 16 + (lane & 15);
    const int lcol = wc * 16 + (lane & 15);
    const float b0 = bg[0 * UU + ucol];
    const float b1 = bg[1 * UU + ucol];
    const float b2 = bg[2 * UU + ucol];
    const float b3 = bg[3 * UU + ucol];
    const float b4 = bg[4 * UU + ucol];
    const int r0 = brow + wr * 64 + ((lane >> 4) << 2);
    const int lr0 = wr * 64 + ((lane >> 4) << 2);
    float* out0 = out;
    float* out1 = out + (size_t)GM * UU;
    float* out2 = out + 2 * (size_t)GM * UU;
#pragma unroll
    for (int m = 0; m < 4; m++) {
#pragma unroll
        for (int j = 0; j < 4; j++) {
            const int row = r0 + m * 16 + j;
            const size_t idx = (size_t)row * UU + ucol;
            const float vs  = lv[(size_t)(lr0 + m * 16 + j) * 36 + lcol];
            const float mtm = m_tm[idx];
            const float f = acc[m][0][j] + b0;
            const float i = acc[m][1][j] + b1;
            const float o = acc[m][2][j] + b2;
            const float g = acc[m][3][j] + b3;
            const float a = acc[m][4][j] + b4;
            const float ft = 1.f / (1.f + __expf(-f));
            const float it = 1.f / (1.f + __expf(-i));
            const float ot = 1.f / (1.f + __expf(-o));
            const float gt = 1.f / (1.f + __expf(-g));
            const float at = tanhf(a);
            const float mtv = mtm * ft + it * at;
            const float tm  = tanhf(mtv);
            const float ht  = ot * tm;
            const float st  = gt * tm;
            out0[idx] = ht + vs + st;
            out1[idx] = ht;
            out2[idx] = mtv;
        }
    }
}

// ---------------------------------------------------------------------------
extern "C" void kernel_launch(void* const* d_in, const int* in_sizes, int n_in,
                              void* d_out, int out_size, void* d_ws, size_t ws_size,
                              hipStream_t stream) {
    (void)in_sizes; (void)n_in; (void)out_size; (void)ws_size;
    const float* inputs  = (const float*)d_in[0];
    const float* h_tm    = (const float*)d_in[1];
    const float* m_tm    = (const float*)d_in[2];
    const float* v_seq   = (const float*)d_in[3];
    const float* W_gates = (const float*)d_in[4];
    const float* U_gates = (const float*)d_in[5];
    const float* b_gates = (const float*)d_in[6];
    // d_in[7..9] (W_z, U_z, W_h) are dead: softmax over a size-1 axis == 1.

    char* ws = (char*)d_ws;
    unsigned short* Abf = (unsigned short*)ws;                  // 2048*3072*2 = 12,582,912 B
    unsigned short* Wt  = (unsigned short*)(ws + 12582912);     // 5120*3072*2 = 31,457,280 B
    float* out = (float*)d_out;

    hipLaunchKernelGGL(prep, dim3(6144 + (GK / 32) * (GN / 32)), dim3(256), 0, stream,
                       h_tm, inputs, W_gates, U_gates, Abf, Wt);
    hipLaunchKernelGGL(gemm_fused, dim3(UU / 32, GM / 128), dim3(256), 0, stream,
                       Abf, Wt, m_tm, b_gates, v_seq, out);
}

// Round 4
// 194.905 us; speedup vs baseline: 1.3103x; 1.0740x over previous
//
#include <hip/hip_runtime.h>
#include <stdint.h>

// Problem constants
#define BB   2048
#define DIN  2048
#define UU   1024
#define KF   49
#define GM   2048         // GEMM M = batch
#define GK   3072         // GEMM K = UU + DIN
#define GN   5120         // GEMM N = 5*UU

// GEMM block geometry
#define BM    128         // batch rows per block
#define UC    64          // unit-cols per block
#define BROWS 320         // Wt2 rows per block = UC*5
#define BKS   32          // K per step
#define NST   96          // K steps
#define BUFB  28672       // LDS byte offset of buffer 1 (A 8KB + B 20KB per buffer)

typedef __bf16  bf16x8 __attribute__((ext_vector_type(8)));
typedef float   f32x4  __attribute__((ext_vector_type(4)));

static __device__ __forceinline__ unsigned short f2bf(float f) {
    union { float f; unsigned u; } x; x.f = f;
    unsigned u = x.u;
    unsigned r = (u + 0x7fffu + ((u >> 16) & 1u)) >> 16;   // RNE
    return (unsigned short)r;
}

// ---------------------------------------------------------------------------
// Kernel 1: prep = buildA (blocks [0,6144)) + buildW transpose (blocks [6144,21504))
//   A[b][k]       = bf16([h_tm | inputs])                        [GM][GK]
//   Wt2[u*5+g][k] = bf16(k<UU ? W_gates[k][g*UU+u] : U_gates[k-UU][g*UU+u])
//   (ucol-major, gates adjacent: one GEMM block's 320 B-rows are contiguous)
// ---------------------------------------------------------------------------
__global__ void prep(const float* __restrict__ h, const float* __restrict__ x,
                     const float* __restrict__ Wg, const float* __restrict__ Ug,
                     unsigned short* __restrict__ A, unsigned short* __restrict__ Wt) {
    __shared__ float t[32][36];
    if (blockIdx.x < 6144) {
        int idx = blockIdx.x * 256 + threadIdx.x;    // one thread = 4 elems
        int b = idx / (GK / 4);
        int k = (idx % (GK / 4)) * 4;
        float4 v;
        if (k < UU) v = *(const float4*)(h + (size_t)b * UU + k);
        else        v = *(const float4*)(x + (size_t)b * DIN + (k - UU));
        ushort4 o;
        o.x = f2bf(v.x); o.y = f2bf(v.y); o.z = f2bf(v.z); o.w = f2bf(v.w);
        *(ushort4*)(A + (size_t)idx * 4) = o;
    } else {
        int bid2 = blockIdx.x - 6144;                // 32x32 transpose tiles
        int k0 = (bid2 % (GK / 32)) * 32;
        int n0 = (bid2 / (GK / 32)) * 32;
        int r  = threadIdx.x >> 3;                   // 0..31
        int cq = threadIdx.x & 7;                    // 0..7  (x4 floats)
        int k = k0 + r;
        const float* src = (k < UU) ? (Wg + (size_t)k * GN) : (Ug + (size_t)(k - UU) * GN);
        *(float4*)&t[r][cq * 4] = *(const float4*)(src + n0 + cq * 4);
        __syncthreads();
        int n = n0 + r;                              // original col = g*UU + u
        int u = n & (UU - 1);
        int g = n >> 10;
        ushort4 o;
        o.x = f2bf(t[cq * 4 + 0][r]);
        o.y = f2bf(t[cq * 4 + 1][r]);
        o.z = f2bf(t[cq * 4 + 2][r]);
        o.w = f2bf(t[cq * 4 + 3][r]);
        *(ushort4*)(Wt + (size_t)(u * 5 + g) * GK + k0 + cq * 4) = o;
    }
}

// ---------------------------------------------------------------------------
// Kernel 2: fused 5-gate GEMM + v_seq reduction + LSTM tail.
// 128 rows x 64 ucols x 5 gates per block; 512 threads (8 waves, 2Mx4N);
// grid 16x16 = 256 blocks = 1/CU. Double-buffered LDS, prefetch next K-step
// at iter top, consume after MFMA (T3 minimum 2-phase). v_seq: 2 float4/iter
// issued at top, accumulated after MFMA (latency hidden), k=48 in epilogue.
// ---------------------------------------------------------------------------
__global__ __launch_bounds__(512, 2) void gemm_fused(
        const unsigned short* __restrict__ A, const unsigned short* __restrict__ Wt,
        const float* __restrict__ m_tm, const float* __restrict__ bg,
        const float* __restrict__ v_seq, float* __restrict__ out) {
    // per buffer: A tile [128][32]bf16 = 8KB | B tile [320][32]bf16 = 20KB
    __shared__ __align__(16) char lds[2 * 28672];

    const int tid  = threadIdx.x;
    const int lane = tid & 63;
    const int wave = tid >> 6;          // 0..7
    const int wr = wave >> 2;           // 0..1 (row half)
    const int wc = wave & 3;            // 0..3 (ucol quarter)
    const int brow  = blockIdx.y * BM;
    const int ucol0 = blockIdx.x * UC;

    f32x4 acc[4][5];
#pragma unroll
    for (int m = 0; m < 4; m++)
#pragma unroll
        for (int g = 0; g < 5; g++) acc[m][g] = (f32x4){0.f, 0.f, 0.f, 0.f};

    // staging: 1792 chunks of 16B per step (A 512, B 1280); round t chunk j=t*512+tid
    const unsigned short* src[4];
    int ldsoff[4];
#pragma unroll
    for (int t = 0; t < 4; t++) {
        int j = t * 512 + tid;
        if (j < 512) {
            src[t] = A + (size_t)(brow + (j >> 2)) * GK + (j & 3) * 8;
            ldsoff[t] = j * 16;
        } else {
            int jj = j - 512;
            if (jj > 1279) jj = 1279;              // clamp; such threads never issue
            src[t] = Wt + (size_t)((size_t)ucol0 * 5 + (jj >> 2)) * GK + (jj & 3) * 8;
            ldsoff[t] = 8192 + jj * 16;
        }
    }

    const int aoff = (wr * 64 + (lane & 15)) * 64 + (lane >> 4) * 16;
    const int boff = 8192 + ((wc * 16 + (lane & 15)) * 5) * 64 + (lane >> 4) * 16;

    auto STAGE = [&](int kstep, int bufbase) {
        const int koff = kstep * BKS;
#pragma unroll
        for (int t = 0; t < 3; t++)
            __builtin_amdgcn_global_load_lds(
                (const __attribute__((address_space(1))) void*)(src[t] + koff),
                (__attribute__((address_space(3))) void*)(lds + bufbase + ldsoff[t]), 16, 0, 0);
        if (tid < 256)
            __builtin_amdgcn_global_load_lds(
                (const __attribute__((address_space(1))) void*)(src[3] + koff),
                (__attribute__((address_space(3))) void*)(lds + bufbase + ldsoff[3]), 16, 0, 0);
    };

    auto COMPUTE = [&](int bufbase) {
        bf16x8 af[4], bfr[5];
#pragma unroll
        for (int m = 0; m < 4; m++) af[m]  = *(const bf16x8*)(lds + bufbase + aoff + m * 1024);
#pragma unroll
        for (int g = 0; g < 5; g++) bfr[g] = *(const bf16x8*)(lds + bufbase + boff + g * 64);
#pragma unroll
        for (int m = 0; m < 4; m++)
#pragma unroll
            for (int g = 0; g < 5; g++)
                acc[m][g] = __builtin_amdgcn_mfma_f32_16x16x32_bf16(af[m], bfr[g], acc[m][g], 0, 0, 0);
    };

    // v_seq: thread covers rows (tid>>4)+{0,32,64,96}, float4-col tid&15
    const float* vp = v_seq + (size_t)(brow + (tid >> 4)) * (KF * UU) + ucol0 + (tid & 15) * 4;
    const size_t RG = (size_t)32 * KF * UU;
    float4 vacc0 = {0,0,0,0}, vacc1 = {0,0,0,0}, vacc2 = {0,0,0,0}, vacc3 = {0,0,0,0};

    STAGE(0, 0);
    __syncthreads();

    for (int tp = 0; tp < 48; ++tp) {
        {   // even step 2tp: consume buf0, stage 2tp+1 -> buf1
            STAGE(2 * tp + 1, BUFB);
            const float4 v0 = *(const float4*)(vp + (size_t)tp * UU);
            const float4 v1 = *(const float4*)(vp + RG + (size_t)tp * UU);
            COMPUTE(0);
            vacc0.x += v0.x; vacc0.y += v0.y; vacc0.z += v0.z; vacc0.w += v0.w;
            vacc1.x += v1.x; vacc1.y += v1.y; vacc1.z += v1.z; vacc1.w += v1.w;
            __syncthreads();
        }
        {   // odd step 2tp+1: consume buf1, stage 2tp+2 -> buf0
            if (tp < 47) STAGE(2 * tp + 2, 0);
            const float4 v2 = *(const float4*)(vp + 2 * RG + (size_t)tp * UU);
            const float4 v3 = *(const float4*)(vp + 3 * RG + (size_t)tp * UU);
            COMPUTE(BUFB);
            vacc2.x += v2.x; vacc2.y += v2.y; vacc2.z += v2.z; vacc2.w += v2.w;
            vacc3.x += v3.x; vacc3.y += v3.y; vacc3.z += v3.z; vacc3.w += v3.w;
            __syncthreads();
        }
    }

    // leftover v_seq k = 48
    {
        const float4 w0 = *(const float4*)(vp + (size_t)48 * UU);
        const float4 w1 = *(const float4*)(vp + RG + (size_t)48 * UU);
        const float4 w2 = *(const float4*)(vp + 2 * RG + (size_t)48 * UU);
        const float4 w3 = *(const float4*)(vp + 3 * RG + (size_t)48 * UU);
        vacc0.x += w0.x; vacc0.y += w0.y; vacc0.z += w0.z; vacc0.w += w0.w;
        vacc1.x += w1.x; vacc1.y += w1.y; vacc1.z += w1.z; vacc1.w += w1.w;
        vacc2.x += w2.x; vacc2.y += w2.y; vacc2.z += w2.z; vacc2.w += w2.w;
        vacc3.x += w3.x; vacc3.y += w3.y; vacc3.z += w3.z; vacc3.w += w3.w;
    }

    // exchange v-sums via LDS: lv[128][68] floats (34.8KB, reuses buffers)
    float* lv = (float*)lds;
    {
        const int xr = tid >> 4, xc = (tid & 15) * 4;
        *(float4*)&lv[(size_t)(xr +  0) * 68 + xc] = vacc0;
        *(float4*)&lv[(size_t)(xr + 32) * 68 + xc] = vacc1;
        *(float4*)&lv[(size_t)(xr + 64) * 68 + xc] = vacc2;
        *(float4*)&lv[(size_t)(xr + 96) * 68 + xc] = vacc3;
    }
    __syncthreads();

    // Epilogue: gates + cell + sentinel + ct, write 3 outputs.
    const int ucol = ucol0 + wc * 16 + (lane & 15);
    const int lcol = wc * 16 + (lane & 15);
    const float b0 = bg[0 * UU + ucol];
    const float b1 = bg[1 * UU + ucol];
    const float b2 = bg[2 * UU + ucol];
    const float b3 = bg[3 * UU + ucol];
    const float b4 = bg[4 * UU + ucol];
    const int lr0 = wr * 64 + ((lane >> 4) << 2);
    float* out0 = out;
    float* out1 = out + (size_t)GM * UU;
    float* out2 = out + 2 * (size_t)GM * UU;
#pragma unroll
    for (int m = 0; m < 4; m++) {
#pragma unroll
        for (int j = 0; j < 4; j++) {
            const int lrow = lr0 + m * 16 + j;
            const int row  = brow + lrow;
            const size_t idx = (size_t)row * UU + ucol;
            const float vs  = lv[(size_t)lrow * 68 + lcol];
            const float mtm = m_tm[idx];
            const float f = acc[m][0][j] + b0;
            const float i = acc[m][1][j] + b1;
            const float o = acc[m][2][j] + b2;
            const float g = acc[m][3][j] + b3;
            const float a = acc[m][4][j] + b4;
            const float ft = 1.f / (1.f + __expf(-f));
            const float it = 1.f / (1.f + __expf(-i));
            const float ot = 1.f / (1.f + __expf(-o));
            const float gt = 1.f / (1.f + __expf(-g));
            const float at = tanhf(a);
            const float mtv = mtm * ft + it * at;
            const float tm  = tanhf(mtv);
            const float ht  = ot * tm;
            const float st  = gt * tm;
            out0[idx] = ht + vs + st;
            out1[idx] = ht;
            out2[idx] = mtv;
        }
    }
}

// ---------------------------------------------------------------------------
extern "C" void kernel_launch(void* const* d_in, const int* in_sizes, int n_in,
                              void* d_out, int out_size, void* d_ws, size_t ws_size,
                              hipStream_t stream) {
    (void)in_sizes; (void)n_in; (void)out_size; (void)ws_size;
    const float* inputs  = (const float*)d_in[0];
    const float* h_tm    = (const float*)d_in[1];
    const float* m_tm    = (const float*)d_in[2];
    const float* v_seq   = (const float*)d_in[3];
    const float* W_gates = (const float*)d_in[4];
    const float* U_gates = (const float*)d_in[5];
    const float* b_gates = (const float*)d_in[6];
    // d_in[7..9] (W_z, U_z, W_h) are dead: softmax over a size-1 axis == 1.

    char* ws = (char*)d_ws;
    unsigned short* Abf = (unsigned short*)ws;                  // 2048*3072*2 = 12,582,912 B
    unsigned short* Wt  = (unsigned short*)(ws + 12582912);     // 5120*3072*2 = 31,457,280 B
    float* out = (float*)d_out;

    hipLaunchKernelGGL(prep, dim3(6144 + (GK / 32) * (GN / 32)), dim3(256), 0, stream,
                       h_tm, inputs, W_gates, U_gates, Abf, Wt);
    hipLaunchKernelGGL(gemm_fused, dim3(UU / UC, GM / BM), dim3(512), 0, stream,
                       Abf, Wt, m_tm, b_gates, v_seq, out);
}

// Round 5
// 182.173 us; speedup vs baseline: 1.4019x; 1.0699x over previous
//
#include <hip/hip_runtime.h>
#include <stdint.h>

// Problem constants
#define BB   2048
#define DIN  2048
#define UU   1024
#define KF   49
#define GM   2048         // GEMM M = batch
#define GK   3072         // GEMM K = UU + DIN
#define GN   5120         // GEMM N = 5*UU

// GEMM block geometry
#define BM    128         // batch rows per block
#define UC    64          // unit-cols per block
#define BKS   32          // K per step
#define NST   96          // K steps
#define SZBUF 28672       // bytes per LDS buffer (A 8KB + B 20KB)

typedef __bf16  bf16x8 __attribute__((ext_vector_type(8)));
typedef float   f32x4  __attribute__((ext_vector_type(4)));

// inline-asm HBM load: keeps FIFO position explicit, compiler can't reorder
#define VL(dst, ptr) asm volatile("global_load_dwordx4 %0, %1, off" \
                                  : "=v"(dst) : "v"(ptr) : "memory")

static __device__ __forceinline__ unsigned short f2bf(float f) {
    union { float f; unsigned u; } x; x.f = f;
    unsigned u = x.u;
    unsigned r = (u + 0x7fffu + ((u >> 16) & 1u)) >> 16;   // RNE
    return (unsigned short)r;
}

// ---------------------------------------------------------------------------
// Kernel 1: prep = buildA (blocks [0,6144)) + buildW transpose (blocks [6144,21504))
//   A[b][k]       = bf16([h_tm | inputs])                        [GM][GK]
//   Wt2[u*5+g][k] = bf16(k<UU ? W_gates[k][g*UU+u] : U_gates[k-UU][g*UU+u])
// ---------------------------------------------------------------------------
__global__ void prep(const float* __restrict__ h, const float* __restrict__ x,
                     const float* __restrict__ Wg, const float* __restrict__ Ug,
                     unsigned short* __restrict__ A, unsigned short* __restrict__ Wt) {
    __shared__ float t[32][36];
    if (blockIdx.x < 6144) {
        int idx = blockIdx.x * 256 + threadIdx.x;    // one thread = 4 elems
        int b = idx / (GK / 4);
        int k = (idx % (GK / 4)) * 4;
        float4 v;
        if (k < UU) v = *(const float4*)(h + (size_t)b * UU + k);
        else        v = *(const float4*)(x + (size_t)b * DIN + (k - UU));
        ushort4 o;
        o.x = f2bf(v.x); o.y = f2bf(v.y); o.z = f2bf(v.z); o.w = f2bf(v.w);
        *(ushort4*)(A + (size_t)idx * 4) = o;
    } else {
        int bid2 = blockIdx.x - 6144;                // 32x32 transpose tiles
        int k0 = (bid2 % (GK / 32)) * 32;
        int n0 = (bid2 / (GK / 32)) * 32;
        int r  = threadIdx.x >> 3;                   // 0..31
        int cq = threadIdx.x & 7;                    // 0..7  (x4 floats)
        int k = k0 + r;
        const float* src = (k < UU) ? (Wg + (size_t)k * GN) : (Ug + (size_t)(k - UU) * GN);
        *(float4*)&t[r][cq * 4] = *(const float4*)(src + n0 + cq * 4);
        __syncthreads();
        int n = n0 + r;                              // original col = g*UU + u
        int u = n & (UU - 1);
        int g = n >> 10;
        ushort4 o;
        o.x = f2bf(t[cq * 4 + 0][r]);
        o.y = f2bf(t[cq * 4 + 1][r]);
        o.z = f2bf(t[cq * 4 + 2][r]);
        o.w = f2bf(t[cq * 4 + 3][r]);
        *(ushort4*)(Wt + (size_t)(u * 5 + g) * GK + k0 + cq * 4) = o;
    }
}

// ---------------------------------------------------------------------------
// Kernel 2: fused 5-gate GEMM + v_seq reduction + LSTM tail, T4 counted-vmcnt
// pipeline. 128 rows x 64 ucols x 5 gates; 512 threads (8 waves 2Mx4N);
// grid 16x16 = 256 blocks = 1/CU. 2 LDS buffers; per iter:
//   consume V(t) -> STAGE(t+1) -> VLOAD(t+2, asm) -> ds_read+MFMA
//   -> s_waitcnt vmcnt(2) (stage drained, v-load stays in flight) -> s_barrier
// ---------------------------------------------------------------------------
__global__ __launch_bounds__(512, 2) void gemm_fused(
        const unsigned short* __restrict__ A, const unsigned short* __restrict__ Wt,
        const float* __restrict__ m_tm, const float* __restrict__ bg,
        const float* __restrict__ v_seq, float* __restrict__ out) {
    // per buffer: A tile [128][32]bf16 = 8KB | B tile [320][32]bf16 = 20KB
    __shared__ __align__(16) char lds[2 * SZBUF];

    const int tid  = threadIdx.x;
    const int lane = tid & 63;
    const int wave = tid >> 6;          // 0..7
    const int wr = wave >> 2;           // 0..1 (row half)
    const int wc = wave & 3;            // 0..3 (ucol quarter)
    const int brow  = blockIdx.y * BM;
    const int ucol0 = blockIdx.x * UC;

    f32x4 acc[4][5];
#pragma unroll
    for (int m = 0; m < 4; m++)
#pragma unroll
        for (int g = 0; g < 5; g++) acc[m][g] = (f32x4){0.f, 0.f, 0.f, 0.f};

    // staging: 1792 chunks of 16B per step (A 512, B 1280); round t chunk j=t*512+tid
    const unsigned short* src[4];
    int ldsoff[4];
#pragma unroll
    for (int t = 0; t < 4; t++) {
        int j = t * 512 + tid;
        if (j < 512) {
            src[t] = A + (size_t)(brow + (j >> 2)) * GK + (j & 3) * 8;
            ldsoff[t] = j * 16;
        } else {
            int jj = j - 512;
            if (jj > 1279) jj = 1279;              // clamp; such threads never issue
            src[t] = Wt + (size_t)((size_t)ucol0 * 5 + (jj >> 2)) * GK + (jj & 3) * 8;
            ldsoff[t] = 8192 + jj * 16;
        }
    }

    const int aoff = (wr * 64 + (lane & 15)) * 64 + (lane >> 4) * 16;
    const int boff = 8192 + ((wc * 16 + (lane & 15)) * 5) * 64 + (lane >> 4) * 16;

    auto STAGE = [&](int kstep, int bufbase) {
        const int koff = kstep * BKS;
#pragma unroll
        for (int t = 0; t < 3; t++)
            __builtin_amdgcn_global_load_lds(
                (const __attribute__((address_space(1))) void*)(src[t] + koff),
                (__attribute__((address_space(3))) void*)(lds + bufbase + ldsoff[t]), 16, 0, 0);
        if (tid < 256)
            __builtin_amdgcn_global_load_lds(
                (const __attribute__((address_space(1))) void*)(src[3] + koff),
                (__attribute__((address_space(3))) void*)(lds + bufbase + ldsoff[3]), 16, 0, 0);
    };

    auto COMPUTE = [&](int bufbase) {
        bf16x8 af[4], bfr[5];
#pragma unroll
        for (int m = 0; m < 4; m++) af[m]  = *(const bf16x8*)(lds + bufbase + aoff + m * 1024);
#pragma unroll
        for (int g = 0; g < 5; g++) bfr[g] = *(const bf16x8*)(lds + bufbase + boff + g * 64);
#pragma unroll
        for (int m = 0; m < 4; m++)
#pragma unroll
            for (int g = 0; g < 5; g++)
                acc[m][g] = __builtin_amdgcn_mfma_f32_16x16x32_bf16(af[m], bfr[g], acc[m][g], 0, 0, 0);
    };

    // v_seq: thread covers rows (tid>>4)+{0,32,64,96}, float4-col tid&15
    const float* vp = v_seq + (size_t)(brow + (tid >> 4)) * (KF * UU) + ucol0 + (tid & 15) * 4;
    const size_t RG = (size_t)32 * KF * UU;
    f32x4 vacc0 = {0,0,0,0}, vacc1 = {0,0,0,0}, vacc2 = {0,0,0,0}, vacc3 = {0,0,0,0};
    f32x4 slA0, slA1, slB0, slB1;

    // prologue: V(0)->slA (rg0,1 k0), V(1)->slB (rg2,3 k0), STAGE(0)->buf0, full drain
    VL(slA0, vp);
    VL(slA1, vp + RG);
    VL(slB0, vp + 2 * RG);
    VL(slB1, vp + 3 * RG);
    STAGE(0, 0);
    asm volatile("s_waitcnt vmcnt(0)" ::: "memory");
    __builtin_amdgcn_s_barrier();
    __builtin_amdgcn_sched_barrier(0);

    for (int tp = 0; tp < 47; ++tp) {
        {   // even t = 2tp: consume slA(k=tp), stage S(t+1)->buf1, load slA<-k=tp+1
            vacc0 += slA0; vacc1 += slA1;
            STAGE(2 * tp + 1, SZBUF);
            VL(slA0, vp + (size_t)(tp + 1) * UU);
            VL(slA1, vp + RG + (size_t)(tp + 1) * UU);
            COMPUTE(0);
            asm volatile("s_waitcnt vmcnt(2)" ::: "memory");
            __builtin_amdgcn_s_barrier();
            __builtin_amdgcn_sched_barrier(0);
        }
        {   // odd t = 2tp+1: consume slB(k=tp), stage S(t+1)->buf0, load slB<-k=tp+1
            vacc2 += slB0; vacc3 += slB1;
            STAGE(2 * tp + 2, 0);
            VL(slB0, vp + 2 * RG + (size_t)(tp + 1) * UU);
            VL(slB1, vp + 3 * RG + (size_t)(tp + 1) * UU);
            COMPUTE(SZBUF);
            asm volatile("s_waitcnt vmcnt(2)" ::: "memory");
            __builtin_amdgcn_s_barrier();
            __builtin_amdgcn_sched_barrier(0);
        }
    }
    // t = 94: consume slA(k=47), stage S(95)->buf1, no vload
    vacc0 += slA0; vacc1 += slA1;
    STAGE(95, SZBUF);
    COMPUTE(0);
    asm volatile("s_waitcnt vmcnt(0)" ::: "memory");
    __builtin_amdgcn_s_barrier();
    __builtin_amdgcn_sched_barrier(0);
    // t = 95: consume slB(k=47)
    vacc2 += slB0; vacc3 += slB1;
    COMPUTE(SZBUF);
    __syncthreads();

    // leftover v_seq k = 48 (plain loads; pipeline drained)
    {
        const float4 w0 = *(const float4*)(vp + (size_t)48 * UU);
        const float4 w1 = *(const float4*)(vp + RG + (size_t)48 * UU);
        const float4 w2 = *(const float4*)(vp + 2 * RG + (size_t)48 * UU);
        const float4 w3 = *(const float4*)(vp + 3 * RG + (size_t)48 * UU);
        vacc0.x += w0.x; vacc0.y += w0.y; vacc0.z += w0.z; vacc0.w += w0.w;
        vacc1.x += w1.x; vacc1.y += w1.y; vacc1.z += w1.z; vacc1.w += w1.w;
        vacc2.x += w2.x; vacc2.y += w2.y; vacc2.z += w2.z; vacc2.w += w2.w;
        vacc3.x += w3.x; vacc3.y += w3.y; vacc3.z += w3.z; vacc3.w += w3.w;
    }

    // exchange v-sums via LDS: lv[128][68] floats (34.8KB, reuses buffers)
    float* lv = (float*)lds;
    {
        const int xr = tid >> 4, xc = (tid & 15) * 4;
        *(f32x4*)&lv[(size_t)(xr +  0) * 68 + xc] = vacc0;
        *(f32x4*)&lv[(size_t)(xr + 32) * 68 + xc] = vacc1;
        *(f32x4*)&lv[(size_t)(xr + 64) * 68 + xc] = vacc2;
        *(f32x4*)&lv[(size_t)(xr + 96) * 68 + xc] = vacc3;
    }
    __syncthreads();

    // Epilogue: gates + cell + sentinel + ct, write 3 outputs.
    const int ucol = ucol0 + wc * 16 + (lane & 15);
    const int lcol = wc * 16 + (lane & 15);
    const float b0 = bg[0 * UU + ucol];
    const float b1 = bg[1 * UU + ucol];
    const float b2 = bg[2 * UU + ucol];
    const float b3 = bg[3 * UU + ucol];
    const float b4 = bg[4 * UU + ucol];
    const int lr0 = wr * 64 + ((lane >> 4) << 2);
    float* out0 = out;
    float* out1 = out + (size_t)GM * UU;
    float* out2 = out + 2 * (size_t)GM * UU;
#pragma unroll
    for (int m = 0; m < 4; m++) {
#pragma unroll
        for (int j = 0; j < 4; j++) {
            const int lrow = lr0 + m * 16 + j;
            const int row  = brow + lrow;
            const size_t idx = (size_t)row * UU + ucol;
            const float vs  = lv[(size_t)lrow * 68 + lcol];
            const float mtm = m_tm[idx];
            const float f = acc[m][0][j] + b0;
            const float i = acc[m][1][j] + b1;
            const float o = acc[m][2][j] + b2;
            const float g = acc[m][3][j] + b3;
            const float a = acc[m][4][j] + b4;
            const float ft = 1.f / (1.f + __expf(-f));
            const float it = 1.f / (1.f + __expf(-i));
            const float ot = 1.f / (1.f + __expf(-o));
            const float gt = 1.f / (1.f + __expf(-g));
            const float at = tanhf(a);
            const float mtv = mtm * ft + it * at;
            const float tm  = tanhf(mtv);
            const float ht  = ot * tm;
            const float st  = gt * tm;
            out0[idx] = ht + vs + st;
            out1[idx] = ht;
            out2[idx] = mtv;
        }
    }
}

// ---------------------------------------------------------------------------
extern "C" void kernel_launch(void* const* d_in, const int* in_sizes, int n_in,
                              void* d_out, int out_size, void* d_ws, size_t ws_size,
                              hipStream_t stream) {
    (void)in_sizes; (void)n_in; (void)out_size; (void)ws_size;
    const float* inputs  = (const float*)d_in[0];
    const float* h_tm    = (const float*)d_in[1];
    const float* m_tm    = (const float*)d_in[2];
    const float* v_seq   = (const float*)d_in[3];
    const float* W_gates = (const float*)d_in[4];
    const float* U_gates = (const float*)d_in[5];
    const float* b_gates = (const float*)d_in[6];
    // d_in[7..9] (W_z, U_z, W_h) are dead: softmax over a size-1 axis == 1.

    char* ws = (char*)d_ws;
    unsigned short* Abf = (unsigned short*)ws;                  // 2048*3072*2 = 12,582,912 B
    unsigned short* Wt  = (unsigned short*)(ws + 12582912);     // 5120*3072*2 = 31,457,280 B
    float* out = (float*)d_out;

    hipLaunchKernelGGL(prep, dim3(6144 + (GK / 32) * (GN / 32)), dim3(256), 0, stream,
                       h_tm, inputs, W_gates, U_gates, Abf, Wt);
    hipLaunchKernelGGL(gemm_fused, dim3(UU / UC, GM / BM), dim3(512), 0, stream,
                       Abf, Wt, m_tm, b_gates, v_seq, out);
}

// Round 6
// 181.848 us; speedup vs baseline: 1.4044x; 1.0018x over previous
//
#include <hip/hip_runtime.h>
#include <stdint.h>

// Problem constants
#define BB   2048
#define DIN  2048
#define UU   1024
#define KF   49
#define GM   2048         // GEMM M = batch
#define GK   3072         // GEMM K = UU + DIN
#define GN   5120         // GEMM N = 5*UU

// GEMM block geometry
#define BM    128         // batch rows per block
#define UC    64          // unit-cols per block
#define BKS   32          // K per step
#define SZBUF 28672       // bytes per LDS buffer (A 8KB + B 20KB); 3 buffers

typedef __bf16  bf16x8 __attribute__((ext_vector_type(8)));
typedef float   f32x4  __attribute__((ext_vector_type(4)));

// inline-asm HBM load: explicit FIFO position, compiler can't reorder vs waitcnt
#define VL(dst, ptr) asm volatile("global_load_dwordx4 %0, %1, off" \
                                  : "=v"(dst) : "v"(ptr) : "memory")

static __device__ __forceinline__ unsigned short f2bf(float f) {
    union { float f; unsigned u; } x; x.f = f;
    unsigned u = x.u;
    unsigned r = (u + 0x7fffu + ((u >> 16) & 1u)) >> 16;   // RNE
    return (unsigned short)r;
}

// ---------------------------------------------------------------------------
// Kernel 1: prep = buildA (blocks [0,6144)) + buildW transpose (blocks [6144,21504))
//   A[b][k]       = bf16([h_tm | inputs])                        [GM][GK]
//   Wt2[u*5+g][k] = bf16(k<UU ? W_gates[k][g*UU+u] : U_gates[k-UU][g*UU+u])
// ---------------------------------------------------------------------------
__global__ void prep(const float* __restrict__ h, const float* __restrict__ x,
                     const float* __restrict__ Wg, const float* __restrict__ Ug,
                     unsigned short* __restrict__ A, unsigned short* __restrict__ Wt) {
    __shared__ float t[32][36];
    if (blockIdx.x < 6144) {
        int idx = blockIdx.x * 256 + threadIdx.x;    // one thread = 4 elems
        int b = idx / (GK / 4);
        int k = (idx % (GK / 4)) * 4;
        float4 v;
        if (k < UU) v = *(const float4*)(h + (size_t)b * UU + k);
        else        v = *(const float4*)(x + (size_t)b * DIN + (k - UU));
        ushort4 o;
        o.x = f2bf(v.x); o.y = f2bf(v.y); o.z = f2bf(v.z); o.w = f2bf(v.w);
        *(ushort4*)(A + (size_t)idx * 4) = o;
    } else {
        int bid2 = blockIdx.x - 6144;                // 32x32 transpose tiles
        int k0 = (bid2 % (GK / 32)) * 32;
        int n0 = (bid2 / (GK / 32)) * 32;
        int r  = threadIdx.x >> 3;                   // 0..31
        int cq = threadIdx.x & 7;                    // 0..7  (x4 floats)
        int k = k0 + r;
        const float* src = (k < UU) ? (Wg + (size_t)k * GN) : (Ug + (size_t)(k - UU) * GN);
        *(float4*)&t[r][cq * 4] = *(const float4*)(src + n0 + cq * 4);
        __syncthreads();
        int n = n0 + r;                              // original col = g*UU + u
        int u = n & (UU - 1);
        int g = n >> 10;
        ushort4 o;
        o.x = f2bf(t[cq * 4 + 0][r]);
        o.y = f2bf(t[cq * 4 + 1][r]);
        o.z = f2bf(t[cq * 4 + 2][r]);
        o.w = f2bf(t[cq * 4 + 3][r]);
        *(ushort4*)(Wt + (size_t)(u * 5 + g) * GK + k0 + cq * 4) = o;
    }
}

// ---------------------------------------------------------------------------
// Kernel 2: fused 5-gate GEMM + v_seq reduction + LSTM tail.
// Depth-2 staging pipeline: 3 LDS buffers, per iter t:
//   consume V(t) -> STAGE(t+2)->buf[(t+2)%3] -> VL V(t+2) -> COMPUTE(buf[t%3])
//   -> s_waitcnt vmcnt(6)  (drains S(t+1)+V(t+1); keeps S(t+2)+V(t+2) in flight)
//   -> s_barrier -> sched_barrier(0)
// Every thread issues exactly 4 stage ops (round 3 duplicated across wave halves,
// identical src->identical LDS bytes) so vmcnt(6) is exact for all waves.
// ---------------------------------------------------------------------------
__global__ __launch_bounds__(512, 2) void gemm_fused(
        const unsigned short* __restrict__ A, const unsigned short* __restrict__ Wt,
        const float* __restrict__ m_tm, const float* __restrict__ bg,
        const float* __restrict__ v_seq, float* __restrict__ out) {
    // per buffer: A tile [128][32]bf16 = 8KB | B tile [320][32]bf16 = 20KB
    __shared__ __align__(16) char lds[3 * SZBUF];   // 86016 B -> 1 block/CU

    const int tid  = threadIdx.x;
    const int lane = tid & 63;
    const int wave = tid >> 6;          // 0..7
    const int wr = wave >> 2;           // 0..1 (row half)
    const int wc = wave & 3;            // 0..3 (ucol quarter)
    const int brow  = blockIdx.y * BM;
    const int ucol0 = blockIdx.x * UC;

    f32x4 acc[4][5];
#pragma unroll
    for (int m = 0; m < 4; m++)
#pragma unroll
        for (int g = 0; g < 5; g++) acc[m][g] = (f32x4){0.f, 0.f, 0.f, 0.f};

    // staging chunk map: 1792 chunks of 16B per K-step (A 512, B 1280)
    // rounds 0..2: chunk j = t*512+tid; round 3: B rows 256..319, duplicated halves
    const unsigned short* src[4];
    int ldsoff[4];
#pragma unroll
    for (int t = 0; t < 4; t++) {
        int jj;
        if (t == 0) {
            src[t] = A + (size_t)(brow + (tid >> 2)) * GK + (tid & 3) * 8;
            ldsoff[t] = tid * 16;
            continue;
        } else if (t < 3) {
            jj = (t - 1) * 512 + tid;              // B chunks 0..1023
        } else {
            jj = 1024 + (tid & 255);               // B chunks 1024..1279, duplicated
        }
        src[t] = Wt + (size_t)((size_t)ucol0 * 5 + (jj >> 2)) * GK + (jj & 3) * 8;
        ldsoff[t] = 8192 + jj * 16;
    }

    const int aoff = (wr * 64 + (lane & 15)) * 64 + (lane >> 4) * 16;
    const int boff = 8192 + ((wc * 16 + (lane & 15)) * 5) * 64 + (lane >> 4) * 16;

    auto STAGE = [&](int kstep, int bufbase) {
        const int koff = kstep * BKS;
#pragma unroll
        for (int t = 0; t < 4; t++)
            __builtin_amdgcn_global_load_lds(
                (const __attribute__((address_space(1))) void*)(src[t] + koff),
                (__attribute__((address_space(3))) void*)(lds + bufbase + ldsoff[t]), 16, 0, 0);
    };

    auto COMPUTE = [&](int bufbase) {
        bf16x8 af[4], bfr[5];
#pragma unroll
        for (int m = 0; m < 4; m++) af[m]  = *(const bf16x8*)(lds + bufbase + aoff + m * 1024);
#pragma unroll
        for (int g = 0; g < 5; g++) bfr[g] = *(const bf16x8*)(lds + bufbase + boff + g * 64);
#pragma unroll
        for (int m = 0; m < 4; m++)
#pragma unroll
            for (int g = 0; g < 5; g++)
                acc[m][g] = __builtin_amdgcn_mfma_f32_16x16x32_bf16(af[m], bfr[g], acc[m][g], 0, 0, 0);
    };

    // v_seq: thread covers rows (tid>>4)+{0,32,64,96}, float4-col tid&15
    const float* vp = v_seq + (size_t)(brow + (tid >> 4)) * (KF * UU) + ucol0 + (tid & 15) * 4;
    const size_t RG = (size_t)32 * KF * UU;
    f32x4 vacc0 = {0,0,0,0}, vacc1 = {0,0,0,0}, vacc2 = {0,0,0,0}, vacc3 = {0,0,0,0};
    f32x4 slA0, slA1, slB0, slB1;

    // prologue: S(0)->b0, V(0)->slA, S(1)->b1, V(1)->slB; wait S(0)+V(0); barrier
    STAGE(0, 0);
    VL(slA0, vp);
    VL(slA1, vp + RG);
    STAGE(1, SZBUF);
    VL(slB0, vp + 2 * RG);
    VL(slB1, vp + 3 * RG);
    asm volatile("s_waitcnt vmcnt(6)" ::: "memory");
    __builtin_amdgcn_s_barrier();
    __builtin_amdgcn_sched_barrier(0);

    int cb = 0;                                     // (t%3)*SZBUF for current t
    for (int tp = 0; tp < 47; ++tp) {
        {   // even t = 2tp: consume slA(k=tp); stage t+2; load slA<-k=tp+1
            vacc0 += slA0; vacc1 += slA1;
            int sb = cb + 2 * SZBUF; if (sb >= 3 * SZBUF) sb -= 3 * SZBUF;
            STAGE(2 * tp + 2, sb);
            VL(slA0, vp + (size_t)(tp + 1) * UU);
            VL(slA1, vp + RG + (size_t)(tp + 1) * UU);
            COMPUTE(cb);
            asm volatile("s_waitcnt vmcnt(6)" ::: "memory");
            __builtin_amdgcn_s_barrier();
            __builtin_amdgcn_sched_barrier(0);
            cb += SZBUF; if (cb >= 3 * SZBUF) cb = 0;
        }
        {   // odd t = 2tp+1: consume slB(k=tp); stage t+2; load slB<-k=tp+1
            vacc2 += slB0; vacc3 += slB1;
            int sb = cb + 2 * SZBUF; if (sb >= 3 * SZBUF) sb -= 3 * SZBUF;
            STAGE(2 * tp + 3, sb);
            VL(slB0, vp + 2 * RG + (size_t)(tp + 1) * UU);
            VL(slB1, vp + 3 * RG + (size_t)(tp + 1) * UU);
            COMPUTE(cb);
            asm volatile("s_waitcnt vmcnt(6)" ::: "memory");
            __builtin_amdgcn_s_barrier();
            __builtin_amdgcn_sched_barrier(0);
            cb += SZBUF; if (cb >= 3 * SZBUF) cb = 0;
        }
    }
    // t = 94 (cb = SZBUF): consume slA(k=47); no stage/vl; drain all
    vacc0 += slA0; vacc1 += slA1;
    COMPUTE(cb);
    asm volatile("s_waitcnt vmcnt(0)" ::: "memory");
    __builtin_amdgcn_s_barrier();
    __builtin_amdgcn_sched_barrier(0);
    cb += SZBUF; if (cb >= 3 * SZBUF) cb = 0;
    // t = 95 (cb = 2*SZBUF): consume slB(k=47)
    vacc2 += slB0; vacc3 += slB1;
    COMPUTE(cb);

    // leftover v_seq k = 48 (plain loads; pipeline drained)
    {
        const float4 w0 = *(const float4*)(vp + (size_t)48 * UU);
        const float4 w1 = *(const float4*)(vp + RG + (size_t)48 * UU);
        const float4 w2 = *(const float4*)(vp + 2 * RG + (size_t)48 * UU);
        const float4 w3 = *(const float4*)(vp + 3 * RG + (size_t)48 * UU);
        vacc0.x += w0.x; vacc0.y += w0.y; vacc0.z += w0.z; vacc0.w += w0.w;
        vacc1.x += w1.x; vacc1.y += w1.y; vacc1.z += w1.z; vacc1.w += w1.w;
        vacc2.x += w2.x; vacc2.y += w2.y; vacc2.z += w2.z; vacc2.w += w2.w;
        vacc3.x += w3.x; vacc3.y += w3.y; vacc3.z += w3.z; vacc3.w += w3.w;
    }

    // exchange v-sums via LDS: lv[128][68] floats (34.8KB; buf0/1 free after t=94)
    float* lv = (float*)lds;
    {
        const int xr = tid >> 4, xc = (tid & 15) * 4;
        *(f32x4*)&lv[(size_t)(xr +  0) * 68 + xc] = vacc0;
        *(f32x4*)&lv[(size_t)(xr + 32) * 68 + xc] = vacc1;
        *(f32x4*)&lv[(size_t)(xr + 64) * 68 + xc] = vacc2;
        *(f32x4*)&lv[(size_t)(xr + 96) * 68 + xc] = vacc3;
    }
    __syncthreads();

    // Epilogue: gates + cell + sentinel + ct, write 3 outputs.
    const int ucol = ucol0 + wc * 16 + (lane & 15);
    const int lcol = wc * 16 + (lane & 15);
    const float b0 = bg[0 * UU + ucol];
    const float b1 = bg[1 * UU + ucol];
    const float b2 = bg[2 * UU + ucol];
    const float b3 = bg[3 * UU + ucol];
    const float b4 = bg[4 * UU + ucol];
    const int lr0 = wr * 64 + ((lane >> 4) << 2);
    float* out0 = out;
    float* out1 = out + (size_t)GM * UU;
    float* out2 = out + 2 * (size_t)GM * UU;
#pragma unroll
    for (int m = 0; m < 4; m++) {
#pragma unroll
        for (int j = 0; j < 4; j++) {
            const int lrow = lr0 + m * 16 + j;
            const int row  = brow + lrow;
            const size_t idx = (size_t)row * UU + ucol;
            const float vs  = lv[(size_t)lrow * 68 + lcol];
            const float mtm = m_tm[idx];
            const float f = acc[m][0][j] + b0;
            const float i = acc[m][1][j] + b1;
            const float o = acc[m][2][j] + b2;
            const float g = acc[m][3][j] + b3;
            const float a = acc[m][4][j] + b4;
            const float ft = 1.f / (1.f + __expf(-f));
            const float it = 1.f / (1.f + __expf(-i));
            const float ot = 1.f / (1.f + __expf(-o));
            const float gt = 1.f / (1.f + __expf(-g));
            const float at = tanhf(a);
            const float mtv = mtm * ft + it * at;
            const float tm  = tanhf(mtv);
            const float ht  = ot * tm;
            const float st  = gt * tm;
            out0[idx] = ht + vs + st;
            out1[idx] = ht;
            out2[idx] = mtv;
        }
    }
}

// ---------------------------------------------------------------------------
extern "C" void kernel_launch(void* const* d_in, const int* in_sizes, int n_in,
                              void* d_out, int out_size, void* d_ws, size_t ws_size,
                              hipStream_t stream) {
    (void)in_sizes; (void)n_in; (void)out_size; (void)ws_size;
    const float* inputs  = (const float*)d_in[0];
    const float* h_tm    = (const float*)d_in[1];
    const float* m_tm    = (const float*)d_in[2];
    const float* v_seq   = (const float*)d_in[3];
    const float* W_gates = (const float*)d_in[4];
    const float* U_gates = (const float*)d_in[5];
    const float* b_gates = (const float*)d_in[6];
    // d_in[7..9] (W_z, U_z, W_h) are dead: softmax over a size-1 axis == 1.

    char* ws = (char*)d_ws;
    unsigned short* Abf = (unsigned short*)ws;                  // 2048*3072*2 = 12,582,912 B
    unsigned short* Wt  = (unsigned short*)(ws + 12582912);     // 5120*3072*2 = 31,457,280 B
    float* out = (float*)d_out;

    hipLaunchKernelGGL(prep, dim3(6144 + (GK / 32) * (GN / 32)), dim3(256), 0, stream,
                       h_tm, inputs, W_gates, U_gates, Abf, Wt);
    hipLaunchKernelGGL(gemm_fused, dim3(UU / UC, GM / BM), dim3(512), 0, stream,
                       Abf, Wt, m_tm, b_gates, v_seq, out);
}